// Round 4
// baseline (718.580 us; speedup 1.0000x reference)
//
#include <hip/hip_runtime.h>
#include <hip/hip_bf16.h>
#include <math.h>

#define N_NODES 100000
#define N_EDGES 500000
#define M0 8.0f
#define INV_SQRT32 0.17677669529663687f

#define NB_HIST 1954   // ceil(500000/256)
#define NB_PROJ 1563   // ceil(100000/64)
#define NB_EE   7813   // ceil(500000/64)
#define GRID_MEGA (NB_HIST + NB_PROJ + NB_EE)

typedef __attribute__((ext_vector_type(8))) short bf16x8;
typedef __attribute__((ext_vector_type(4))) float f32x4;
typedef __attribute__((ext_vector_type(8))) unsigned short us8;

static __device__ __forceinline__ unsigned short f2bf(float f) {
    __hip_bfloat16 h = __float2bfloat16(f);
    return *(unsigned short*)&h;
}

static __device__ __forceinline__ void split4(float4 v, ushort4& hv, ushort4& lv) {
    const unsigned short h0 = f2bf(v.x), h1 = f2bf(v.y),
                         h2 = f2bf(v.z), h3 = f2bf(v.w);
    hv.x = h0; hv.y = h1; hv.z = h2; hv.w = h3;
    lv.x = f2bf(v.x - __uint_as_float((unsigned)h0 << 16));
    lv.y = f2bf(v.y - __uint_as_float((unsigned)h1 << 16));
    lv.z = f2bf(v.z - __uint_as_float((unsigned)h2 << 16));
    lv.w = f2bf(v.w - __uint_as_float((unsigned)h3 << 16));
}

// ---------------------------------------------------------------------------
// prep: split weights into bf16 hi/lo (Markidis) AND zero the cursor array.
// ---------------------------------------------------------------------------
__global__ __launch_bounds__(256) void prep_kernel(
    const float* __restrict__ Wq, const float* __restrict__ Wk,
    const float* __restrict__ Wv, const float* __restrict__ Ws,
    const float* __restrict__ We,
    unsigned short* __restrict__ WBh, unsigned short* __restrict__ WBl,
    unsigned short* __restrict__ WEh, unsigned short* __restrict__ WEl,
    int* __restrict__ cursor)
{
    const int i = blockIdx.x * 256 + threadIdx.x;
    if (i < N_NODES) cursor[i] = 0;
    if (i < 65536) {
        const int p = i >> 14;
        const float* W = (p == 0) ? Wq : (p == 1) ? Wk : (p == 2) ? Wv : Ws;
        const float v = W[i & 16383];
        const unsigned short h = f2bf(v);
        WBh[i] = h;
        WBl[i] = f2bf(v - __uint_as_float((unsigned)h << 16));
    } else if (i < 73728) {
        const int idx = i - 65536;
        const float v = We[idx];
        const unsigned short h = f2bf(v);
        WEh[idx] = h;
        WEl[idx] = f2bf(v - __uint_as_float((unsigned)h << 16));
    }
}

// ---------------------------------------------------------------------------
// mega: hist + node-proj MFMA + edge-embed MFMA in one grid.
// Round-4 structure: W-fragments live in REGISTERS loaded from L2 (all
// blocks read identical weight addresses -> L2-hot broadcast). Only the
// per-block x/ea tile is staged in LDS (32 KB hi+lo) -> ONE barrier per
// block (was 9 for proj). MFMA operands swapped (mfma(W,x)) so each lane
// owns 4 consecutive output channels -> float4/ushort4 vector stores.
// ---------------------------------------------------------------------------
__global__ __launch_bounds__(256, 5) void mega_kernel(
    const float* __restrict__ x, const int* __restrict__ ei,
    const float* __restrict__ ea,
    const unsigned short* __restrict__ WBh, const unsigned short* __restrict__ WBl,
    const unsigned short* __restrict__ WEh, const unsigned short* __restrict__ WEl,
    const float* __restrict__ bq, const float* __restrict__ bk,
    const float* __restrict__ bv, const float* __restrict__ bs,
    float* __restrict__ Qn, float* __restrict__ Kn, float* __restrict__ Vn,
    float* __restrict__ out, unsigned short* __restrict__ Ee,
    int* __restrict__ cursor)
{
    __shared__ __align__(16) unsigned short sAh[8192];   // 16 KB
    __shared__ __align__(16) unsigned short sAl[8192];   // 16 KB

    const int t = threadIdx.x;
    const int bid = blockIdx.x;

    // ---- CSR histogram blocks ----
    if (bid < NB_HIST) {
        const int e = bid * 256 + t;
        if (e < N_EDGES) atomicAdd(&cursor[ei[N_EDGES + e]], 1);
        return;
    }

    const int lane = t & 63;
    const int wid = t >> 6;          // 0..3
    const int fr = lane & 15;
    const int fq = lane >> 4;
    const int cb = wid * 32;         // wave's 32 output channels

    if (bid < NB_HIST + NB_PROJ) {
        // ---- node projection: 64 rows x 128 ch x (Q,K,V,S) ----
        const long r0 = (long)(bid - NB_HIST) * 64;

        // stage x tile [64][128] -> hi/lo bf16, swizzled
        for (int i = t; i < 2048; i += 256) {
            const int r = i >> 5;
            const int k4 = (i & 31) * 4;
            const long row = r0 + r;
            float4 v = (row < N_NODES) ? *(const float4*)&x[row * 128 + k4]
                                       : make_float4(0.f, 0.f, 0.f, 0.f);
            ushort4 hv, lv; split4(v, hv, lv);
            const int di = r * 128 + (k4 ^ ((r & 7) << 3));
            *(ushort4*)&sAh[di] = hv;
            *(ushort4*)&sAl[di] = lv;
        }
        __syncthreads();

        for (int p = 0; p < 4; ++p) {
            const float* bias = (p == 0) ? bq : (p == 1) ? bk : (p == 2) ? bv : bs;
            float* dst        = (p == 0) ? Qn : (p == 1) ? Kn : (p == 2) ? Vn : out;

            f32x4 acc[4][2];
#pragma unroll
            for (int m = 0; m < 4; ++m)
#pragma unroll
                for (int n = 0; n < 2; ++n) acc[m][n] = (f32x4){0.f, 0.f, 0.f, 0.f};

#pragma unroll
            for (int kc = 0; kc < 4; ++kc) {
                const int kx = kc * 32 + fq * 8;
                // W frags from global (L2-hot; identical across blocks)
                bf16x8 wh[2], wl[2];
#pragma unroll
                for (int n = 0; n < 2; ++n) {
                    const int gi = p * 16384 + (cb + n * 16 + fr) * 128 + kx;
                    wh[n] = *(const bf16x8*)&WBh[gi];
                    wl[n] = *(const bf16x8*)&WBl[gi];
                }
                // x frags from LDS
                bf16x8 ah[4], al[4];
#pragma unroll
                for (int m = 0; m < 4; ++m) {
                    const int r = m * 16 + fr;
                    const int di = r * 128 + (kx ^ ((r & 7) << 3));
                    ah[m] = *(const bf16x8*)&sAh[di];
                    al[m] = *(const bf16x8*)&sAl[di];
                }
#pragma unroll
                for (int m = 0; m < 4; ++m)
#pragma unroll
                    for (int n = 0; n < 2; ++n) {
                        // D[ch, xrow]: A = W, B = x
                        acc[m][n] = __builtin_amdgcn_mfma_f32_16x16x32_bf16(
                            wh[n], ah[m], acc[m][n], 0, 0, 0);
                        acc[m][n] = __builtin_amdgcn_mfma_f32_16x16x32_bf16(
                            wh[n], al[m], acc[m][n], 0, 0, 0);
                        acc[m][n] = __builtin_amdgcn_mfma_f32_16x16x32_bf16(
                            wl[n], ah[m], acc[m][n], 0, 0, 0);
                    }
            }

            // lane holds chans {cb+n*16+fq*4 .. +3} for x-row m*16+fr
            float4 bb[2];
#pragma unroll
            for (int n = 0; n < 2; ++n)
                bb[n] = *(const float4*)&bias[cb + n * 16 + fq * 4];
#pragma unroll
            for (int m = 0; m < 4; ++m) {
                const long row = r0 + m * 16 + fr;
                if (row < N_NODES) {
#pragma unroll
                    for (int n = 0; n < 2; ++n) {
                        float4 o;
                        o.x = acc[m][n][0] + bb[n].x;
                        o.y = acc[m][n][1] + bb[n].y;
                        o.z = acc[m][n][2] + bb[n].z;
                        o.w = acc[m][n][3] + bb[n].w;
                        *(float4*)&dst[row * 128 + cb + n * 16 + fq * 4] = o;
                    }
                }
            }
        }
    } else {
        // ---- edge embedding GEMM: Ee[64 edges][128 ch] = ea @ We^T ----
        const long e0 = (long)(bid - NB_HIST - NB_PROJ) * 64;

        // stage ea tile [64][64] -> hi/lo bf16, swizzled
        for (int i = t; i < 1024; i += 256) {
            const int r = i >> 4;
            const int k4 = (i & 15) * 4;
            const long e = e0 + r;
            float4 v = (e < N_EDGES) ? *(const float4*)&ea[e * 64 + k4]
                                     : make_float4(0.f, 0.f, 0.f, 0.f);
            ushort4 hv, lv; split4(v, hv, lv);
            const int di = r * 64 + (k4 ^ ((r & 7) << 3));
            *(ushort4*)&sAh[di] = hv;
            *(ushort4*)&sAl[di] = lv;
        }
        __syncthreads();

        f32x4 acc[4][2];
#pragma unroll
        for (int m = 0; m < 4; ++m)
#pragma unroll
            for (int n = 0; n < 2; ++n) acc[m][n] = (f32x4){0.f, 0.f, 0.f, 0.f};

#pragma unroll
        for (int ks = 0; ks < 2; ++ks) {
            const int kk = ks * 32 + fq * 8;
            bf16x8 wh[2], wl[2];
#pragma unroll
            for (int n = 0; n < 2; ++n) {
                const int gi = (cb + n * 16 + fr) * 64 + kk;
                wh[n] = *(const bf16x8*)&WEh[gi];
                wl[n] = *(const bf16x8*)&WEl[gi];
            }
            bf16x8 ah[4], al[4];
#pragma unroll
            for (int m = 0; m < 4; ++m) {
                const int r = m * 16 + fr;
                const int di = r * 64 + (kk ^ ((r & 7) << 3));
                ah[m] = *(const bf16x8*)&sAh[di];
                al[m] = *(const bf16x8*)&sAl[di];
            }
#pragma unroll
            for (int m = 0; m < 4; ++m)
#pragma unroll
                for (int n = 0; n < 2; ++n) {
                    acc[m][n] = __builtin_amdgcn_mfma_f32_16x16x32_bf16(
                        wh[n], ah[m], acc[m][n], 0, 0, 0);
                    acc[m][n] = __builtin_amdgcn_mfma_f32_16x16x32_bf16(
                        wh[n], al[m], acc[m][n], 0, 0, 0);
                    acc[m][n] = __builtin_amdgcn_mfma_f32_16x16x32_bf16(
                        wl[n], ah[m], acc[m][n], 0, 0, 0);
                }
        }

#pragma unroll
        for (int m = 0; m < 4; ++m) {
            const long e = e0 + m * 16 + fr;
            if (e < N_EDGES) {
#pragma unroll
                for (int n = 0; n < 2; ++n) {
                    ushort4 u;
                    u.x = f2bf(acc[m][n][0]);
                    u.y = f2bf(acc[m][n][1]);
                    u.z = f2bf(acc[m][n][2]);
                    u.w = f2bf(acc[m][n][3]);
                    *(ushort4*)&Ee[e * 128 + cb + n * 16 + fq * 4] = u;
                }
            }
        }
    }
}

// ---------------------------------------------------------------------------
// CSR scan: single block, 1024 threads.
// ---------------------------------------------------------------------------
__global__ __launch_bounds__(1024) void csr_scan_kernel(
    int* __restrict__ cursor, int* __restrict__ csr_off)
{
    __shared__ int wsum[16];
    const int t = threadIdx.x;
    const int lane = t & 63;
    const int wid = t >> 6;
    const int n0 = t * 100;
    const bool active = (t < 1000);

    int tsum = 0;
    if (active) {
        for (int q = 0; q < 25; ++q) {
            const int4 d = *(const int4*)&cursor[n0 + q * 4];
            tsum += d.x + d.y + d.z + d.w;
        }
    }
    int inc = tsum;
#pragma unroll
    for (int o = 1; o < 64; o <<= 1) {
        const int v = __shfl_up(inc, o, 64);
        if (lane >= o) inc += v;
    }
    if (lane == 63) wsum[wid] = inc;
    __syncthreads();
    if (t == 0) {
        int run = 0;
#pragma unroll
        for (int w = 0; w < 16; ++w) { const int v = wsum[w]; wsum[w] = run; run += v; }
        csr_off[N_NODES] = run;
    }
    __syncthreads();
    if (active) {
        int run = wsum[wid] + inc - tsum;
        for (int q = 0; q < 25; ++q) {
            const int n = n0 + q * 4;
            const int4 d = *(const int4*)&cursor[n];
            int4 offv;
            offv.x = run; run += d.x;
            offv.y = run; run += d.y;
            offv.z = run; run += d.z;
            offv.w = run; run += d.w;
            *(int4*)&csr_off[n] = offv;
            *(int4*)&cursor[n]  = offv;
        }
    }
}

__global__ __launch_bounds__(256) void csr_fill_kernel(
    const int* __restrict__ ei, int* __restrict__ cursor,
    int* __restrict__ csr_eid, int* __restrict__ csr_src)
{
    const int e = blockIdx.x * 256 + threadIdx.x;
    if (e >= N_EDGES) return;
    const int dst = ei[N_EDGES + e];
    const int pos = atomicAdd(&cursor[dst], 1);
    csr_eid[pos] = e;
    csr_src[pos] = ei[e];
}

// ---------------------------------------------------------------------------
// Fused attention, single pass, 4 edges in flight per wave. Unchanged.
// ---------------------------------------------------------------------------
__global__ __launch_bounds__(256) void fused_attn_kernel(
    const int* __restrict__ csr_off, const int* __restrict__ csr_eid,
    const int* __restrict__ csr_src, const unsigned short* __restrict__ Ee,
    const float* __restrict__ Qn, const float* __restrict__ Kn,
    const float* __restrict__ Vn, float* __restrict__ out)
{
    const int lane = threadIdx.x & 63;
    const int g = lane >> 4;
    const int i2 = (lane & 15) * 2;
    const long n = (long)blockIdx.x * 4 + (threadIdx.x >> 6);

    const int off0 = csr_off[n];
    const int off1 = csr_off[n + 1];

    float2 q[4];
#pragma unroll
    for (int h = 0; h < 4; ++h)
        q[h] = *(const float2*)&Qn[n * 128 + h * 32 + i2];

    float dsum[4] = {0.f, 0.f, 0.f, 0.f};
    float2 acc[4];
#pragma unroll
    for (int h = 0; h < 4; ++h) acc[h] = make_float2(0.f, 0.f);

    for (int base = off0; base < off1; base += 64) {
        const int cnt = min(64, off1 - base);
        int eid = 0, src = 0;
        if (base + lane < off1) {
            eid = csr_eid[base + lane];
            src = csr_src[base + lane];
        }
        for (int c0 = 0; c0 < cnt; c0 += 4) {
            const int j = c0 + g;
            const bool valid = (j < cnt);
            const long e = __shfl(eid, j, 64);
            const long s = __shfl(src, j, 64);

            float ph[4];
            float ea0[4], ea1[4];
            float2 vv[4];
            if (valid) {
#pragma unroll
                for (int h = 0; h < 4; ++h) {
                    const int ch = h * 32 + i2;
                    const unsigned u = *(const unsigned*)&Ee[e * 128 + ch];
                    ea0[h] = __uint_as_float(u << 16);
                    ea1[h] = __uint_as_float(u & 0xffff0000u);
                    const float2 k = *(const float2*)&Kn[s * 128 + ch];
                    vv[h] = *(const float2*)&Vn[s * 128 + ch];
                    ph[h] = q[h].x * (k.x + ea0[h]) + q[h].y * (k.y + ea1[h]);
                }
            } else {
#pragma unroll
                for (int h = 0; h < 4; ++h) ph[h] = 0.f;
            }
#pragma unroll
            for (int h = 0; h < 4; ++h) {
#pragma unroll
                for (int o = 1; o < 16; o <<= 1)
                    ph[h] += __shfl_xor(ph[h], o, 64);
            }
            if (valid) {
#pragma unroll
                for (int h = 0; h < 4; ++h) {
                    const float an = __expf(ph[h] * INV_SQRT32 - M0);
                    dsum[h] += an;
                    acc[h].x = fmaf(vv[h].x + ea0[h], an, acc[h].x);
                    acc[h].y = fmaf(vv[h].y + ea1[h], an, acc[h].y);
                }
            }
        }
    }

#pragma unroll
    for (int h = 0; h < 4; ++h) {
#pragma unroll
        for (int o = 16; o < 64; o <<= 1) {
            dsum[h] += __shfl_xor(dsum[h], o, 64);
            acc[h].x += __shfl_xor(acc[h].x, o, 64);
            acc[h].y += __shfl_xor(acc[h].y, o, 64);
        }
    }

    const float rd = 1.f / (dsum[g] + 1e-16f);
    float2 o = *(const float2*)&out[n * 128 + g * 32 + i2];
    o.x = fmaf(acc[g].x, rd, o.x);
    o.y = fmaf(acc[g].y, rd, o.y);
    *(float2*)&out[n * 128 + g * 32 + i2] = o;
}

// ---------------------------------------------------------------------------
// Workspace layout (float offsets unless noted):
//   Qn      [N,128]   @ 0
//   Kn      [N,128]   @ 12,800,000
//   Vn      [N,128]   @ 25,600,000
//   csr_off [N+1]     @ 38,400,000  (int)
//   cursor  [N]       @ 38,500,004  (int)
//   csr_eid [E]       @ 38,600,004  (int)
//   csr_src [E]       @ 39,100,004  (int)
//   WBh     [65536]us @ 40,000,000
//   WBl     [65536]us @ 40,050,000
//   WEh     [8192]us  @ 40,100,000
//   WEl     [8192]us  @ 40,110,000
//   Ee bf16 [E,128]   @ byte 163,200,032
// ---------------------------------------------------------------------------
extern "C" void kernel_launch(void* const* d_in, const int* in_sizes, int n_in,
                              void* d_out, int out_size, void* d_ws, size_t ws_size,
                              hipStream_t stream)
{
    const float* x  = (const float*)d_in[0];
    const int*   ei = (const int*)d_in[1];
    const float* ea = (const float*)d_in[2];
    const float* Wq = (const float*)d_in[3];
    const float* bq = (const float*)d_in[4];
    const float* Wk = (const float*)d_in[5];
    const float* bk = (const float*)d_in[6];
    const float* Wv = (const float*)d_in[7];
    const float* bv = (const float*)d_in[8];
    const float* We = (const float*)d_in[9];
    const float* Ws = (const float*)d_in[10];
    const float* bs = (const float*)d_in[11];
    float* out = (float*)d_out;

    float* ws = (float*)d_ws;
    float* Qn = ws;
    float* Kn = ws + 12800000;
    float* Vn = ws + 25600000;
    int* csr_off = (int*)(ws + 38400000);
    int* cursor  = (int*)(ws + 38500004);
    int* csr_eid = (int*)(ws + 38600004);
    int* csr_src = (int*)(ws + 39100004);
    unsigned short* WBh = (unsigned short*)(ws + 40000000);
    unsigned short* WBl = (unsigned short*)(ws + 40050000);
    unsigned short* WEh = (unsigned short*)(ws + 40100000);
    unsigned short* WEl = (unsigned short*)(ws + 40110000);
    unsigned short* Ee = (unsigned short*)((char*)d_ws + 163200032);

    prep_kernel<<<391, 256, 0, stream>>>(Wq, Wk, Wv, Ws, We,
                                         WBh, WBl, WEh, WEl, cursor);

    mega_kernel<<<GRID_MEGA, 256, 0, stream>>>(x, ei, ea,
                                               WBh, WBl, WEh, WEl,
                                               bq, bk, bv, bs,
                                               Qn, Kn, Vn, out, Ee, cursor);

    csr_scan_kernel<<<1, 1024, 0, stream>>>(cursor, csr_off);

    csr_fill_kernel<<<(N_EDGES + 255) / 256, 256, 0, stream>>>(ei, cursor,
                                                               csr_eid, csr_src);

    fused_attn_kernel<<<25000, 256, 0, stream>>>(csr_off, csr_eid, csr_src, Ee,
                                                 Qn, Kn, Vn, out);
}

// Round 6
// 601.090 us; speedup vs baseline: 1.1955x; 1.1955x over previous
//
#include <hip/hip_runtime.h>
#include <hip/hip_bf16.h>
#include <math.h>

#define N_NODES 100000
#define N_EDGES 500000
#define M0 8.0f
#define INV_SQRT32 0.17677669529663687f

#define NB_HIST 977    // ceil(500000/512)
#define NB_PROJ 1563   // ceil(100000/64)
#define NB_EE   3907   // ceil(500000/128)
#define GRID_MEGA (NB_HIST + NB_PROJ + NB_EE)

typedef __attribute__((ext_vector_type(8))) short bf16x8;
typedef __attribute__((ext_vector_type(4))) float f32x4;
typedef __attribute__((ext_vector_type(8))) unsigned short us8;

static __device__ __forceinline__ unsigned short f2bf(float f) {
    __hip_bfloat16 h = __float2bfloat16(f);
    return *(unsigned short*)&h;
}

static __device__ __forceinline__ float bf2f(unsigned short u) {
    return __uint_as_float((unsigned)u << 16);
}

static __device__ __forceinline__ void split4(float4 v, ushort4& hv, ushort4& lv) {
    const unsigned short h0 = f2bf(v.x), h1 = f2bf(v.y),
                         h2 = f2bf(v.z), h3 = f2bf(v.w);
    hv.x = h0; hv.y = h1; hv.z = h2; hv.w = h3;
    lv.x = f2bf(v.x - __uint_as_float((unsigned)h0 << 16));
    lv.y = f2bf(v.y - __uint_as_float((unsigned)h1 << 16));
    lv.z = f2bf(v.z - __uint_as_float((unsigned)h2 << 16));
    lv.w = f2bf(v.w - __uint_as_float((unsigned)h3 << 16));
}

// ---------------------------------------------------------------------------
// prep: split weights into bf16 hi/lo (Markidis) AND zero the cursor array.
// ---------------------------------------------------------------------------
__global__ __launch_bounds__(256) void prep_kernel(
    const float* __restrict__ Wq, const float* __restrict__ Wk,
    const float* __restrict__ Wv, const float* __restrict__ Ws,
    const float* __restrict__ We,
    unsigned short* __restrict__ WBh, unsigned short* __restrict__ WBl,
    unsigned short* __restrict__ WEh, unsigned short* __restrict__ WEl,
    int* __restrict__ cursor)
{
    const int i = blockIdx.x * 256 + threadIdx.x;
    if (i < N_NODES) cursor[i] = 0;
    if (i < 65536) {
        const int p = i >> 14;
        const float* W = (p == 0) ? Wq : (p == 1) ? Wk : (p == 2) ? Wv : Ws;
        const float v = W[i & 16383];
        const unsigned short h = f2bf(v);
        WBh[i] = h;
        WBl[i] = f2bf(v - __uint_as_float((unsigned)h << 16));
    } else if (i < 73728) {
        const int idx = i - 65536;
        const float v = We[idx];
        const unsigned short h = f2bf(v);
        WEh[idx] = h;
        WEl[idx] = f2bf(v - __uint_as_float((unsigned)h << 16));
    }
}

// ---------------------------------------------------------------------------
// mega: hist + node-proj MFMA + edge-embed MFMA in one grid.
// Round-5 structure: EXACT Round-3 memory structure (LDS-staged W, proven
// FETCH=92MB) with MFMA operands swapped (A=W, B=x): identical LDS read
// patterns, but D's register index becomes the CHANNEL dim -> float4 /
// ushort4 epilogue stores (16 scalar dwords -> 4 float4; 32 x 2-byte Ee
// stores -> 8 ushort4).
// ---------------------------------------------------------------------------
__global__ __launch_bounds__(512, 4) void mega_kernel(
    const float* __restrict__ x, const int* __restrict__ ei,
    const float* __restrict__ ea,
    const unsigned short* __restrict__ WBh, const unsigned short* __restrict__ WBl,
    const unsigned short* __restrict__ WEh, const unsigned short* __restrict__ WEl,
    const float* __restrict__ bq, const float* __restrict__ bk,
    const float* __restrict__ bv, const float* __restrict__ bs,
    float* __restrict__ Qn, float* __restrict__ Kn, float* __restrict__ Vn,
    float* __restrict__ out, unsigned short* __restrict__ Ee,
    int* __restrict__ cursor)
{
    __shared__ __align__(16) unsigned short sAh[8192];
    __shared__ __align__(16) unsigned short sAl[8192];
    __shared__ __align__(16) unsigned short sWh[8192];
    __shared__ __align__(16) unsigned short sWl[8192];

    const int t = threadIdx.x;
    const int bid = blockIdx.x;

    // ---- CSR histogram blocks ----
    if (bid < NB_HIST) {
        const int e = bid * 512 + t;
        if (e < N_EDGES) atomicAdd(&cursor[ei[N_EDGES + e]], 1);
        return;
    }

    const int lane = t & 63;
    const int wid = t >> 6;          // 0..7
    const int fr = lane & 15;
    const int fq = lane >> 4;

    if (bid < NB_HIST + NB_PROJ) {
        // ---- node projection: 64 rows x (Q,K,V,S); wave owns 16 ch ----
        const long r0 = (long)(bid - NB_HIST) * 64;

        for (int i = t; i < 2048; i += 512) {
            const int r = i >> 5;
            const int k4 = (i & 31) * 4;
            const long row = r0 + r;
            float4 v = (row < N_NODES) ? *(const float4*)&x[row * 128 + k4]
                                       : make_float4(0.f, 0.f, 0.f, 0.f);
            ushort4 hv, lv; split4(v, hv, lv);
            const int di = r * 128 + (k4 ^ ((r & 7) << 3));
            *(ushort4*)&sAh[di] = hv;
            *(ushort4*)&sAl[di] = lv;
        }

        for (int p = 0; p < 4; ++p) {
            const float* bias = (p == 0) ? bq : (p == 1) ? bk : (p == 2) ? bv : bs;
            float* dst        = (p == 0) ? Qn : (p == 1) ? Kn : (p == 2) ? Vn : out;

            // acc[m]: D[ch_reg][xrow_col] for x-rows m*16..m*16+15
            f32x4 acc[4];
#pragma unroll
            for (int m = 0; m < 4; ++m) acc[m] = (f32x4){0.f, 0.f, 0.f, 0.f};

            for (int kc = 0; kc < 2; ++kc) {
                __syncthreads();
                for (int i = t; i < 1024; i += 512) {
                    const int r = i >> 3;
                    const int s = i & 7;
                    const int gi = p * 16384 + r * 128 + kc * 64 + s * 8;
                    const int di = r * 64 + ((s * 8) ^ ((r & 7) << 3));
                    *(us8*)&sWh[di] = *(const us8*)&WBh[gi];
                    *(us8*)&sWl[di] = *(const us8*)&WBl[gi];
                }
                __syncthreads();

#pragma unroll
                for (int ks = 0; ks < 2; ++ks) {
                    const int kx = kc * 64 + ks * 32 + fq * 8;
                    const int kw = ks * 32 + fq * 8;
                    bf16x8 ah[4], al[4], wh, wl;
#pragma unroll
                    for (int m = 0; m < 4; ++m) {
                        const int r = m * 16 + fr;
                        const int di = r * 128 + (kx ^ ((r & 7) << 3));
                        ah[m] = *(const bf16x8*)&sAh[di];
                        al[m] = *(const bf16x8*)&sAl[di];
                    }
                    {
                        const int r = wid * 16 + fr;   // W row = channel
                        const int di = r * 64 + (kw ^ ((r & 7) << 3));
                        wh = *(const bf16x8*)&sWh[di];
                        wl = *(const bf16x8*)&sWl[di];
                    }
#pragma unroll
                    for (int m = 0; m < 4; ++m) {
                        acc[m] = __builtin_amdgcn_mfma_f32_16x16x32_bf16(
                            wh, ah[m], acc[m], 0, 0, 0);
                        acc[m] = __builtin_amdgcn_mfma_f32_16x16x32_bf16(
                            wh, al[m], acc[m], 0, 0, 0);
                        acc[m] = __builtin_amdgcn_mfma_f32_16x16x32_bf16(
                            wl, ah[m], acc[m], 0, 0, 0);
                    }
                }
            }

            // lane holds chans wid*16+fq*4..+3 for x-row m*16+fr
            const float4 bb = *(const float4*)&bias[wid * 16 + fq * 4];
#pragma unroll
            for (int m = 0; m < 4; ++m) {
                const long row = r0 + m * 16 + fr;
                if (row < N_NODES) {
                    float4 o;
                    o.x = acc[m][0] + bb.x;
                    o.y = acc[m][1] + bb.y;
                    o.z = acc[m][2] + bb.z;
                    o.w = acc[m][3] + bb.w;
                    *(float4*)&dst[row * 128 + wid * 16 + fq * 4] = o;
                }
            }
        }
    } else {
        // ---- edge embedding GEMM: 128x128 tile; 8 waves in 2x4 ----
        const long e0 = (long)(bid - NB_HIST - NB_PROJ) * 128;
        const int wr = wid >> 2;     // 0..1: edge rows wr*64
        const int wc = wid & 3;      // 0..3: ch cols wc*32

        for (int i = t; i < 1024; i += 512) {
            const int r = i >> 3;
            const int s = i & 7;
            const int di = r * 64 + ((s * 8) ^ ((r & 7) << 3));
            *(us8*)&sWh[di] = *(const us8*)&WEh[r * 64 + s * 8];
            *(us8*)&sWl[di] = *(const us8*)&WEl[r * 64 + s * 8];
        }
        for (int i = t; i < 2048; i += 512) {
            const int r = i >> 4;
            const int k4 = (i & 15) * 4;
            const long e = e0 + r;
            float4 v = (e < N_EDGES) ? *(const float4*)&ea[e * 64 + k4]
                                     : make_float4(0.f, 0.f, 0.f, 0.f);
            ushort4 hv, lv; split4(v, hv, lv);
            const int di = r * 64 + (k4 ^ ((r & 7) << 3));
            *(ushort4*)&sAh[di] = hv;
            *(ushort4*)&sAl[di] = lv;
        }
        __syncthreads();

        f32x4 acc[4][2];
#pragma unroll
        for (int m = 0; m < 4; ++m)
#pragma unroll
            for (int n = 0; n < 2; ++n) acc[m][n] = (f32x4){0.f, 0.f, 0.f, 0.f};

#pragma unroll
        for (int ks = 0; ks < 2; ++ks) {
            const int kk = ks * 32 + fq * 8;
            bf16x8 ah[4], al[4], wh[2], wl[2];
#pragma unroll
            for (int m = 0; m < 4; ++m) {
                const int r = wr * 64 + m * 16 + fr;
                const int di = r * 64 + (kk ^ ((r & 7) << 3));
                ah[m] = *(const bf16x8*)&sAh[di];
                al[m] = *(const bf16x8*)&sAl[di];
            }
#pragma unroll
            for (int n = 0; n < 2; ++n) {
                const int r = wc * 32 + n * 16 + fr;   // W row = channel
                const int di = r * 64 + (kk ^ ((r & 7) << 3));
                wh[n] = *(const bf16x8*)&sWh[di];
                wl[n] = *(const bf16x8*)&sWl[di];
            }
#pragma unroll
            for (int m = 0; m < 4; ++m)
#pragma unroll
                for (int n = 0; n < 2; ++n) {
                    acc[m][n] = __builtin_amdgcn_mfma_f32_16x16x32_bf16(
                        wh[n], ah[m], acc[m][n], 0, 0, 0);
                    acc[m][n] = __builtin_amdgcn_mfma_f32_16x16x32_bf16(
                        wh[n], al[m], acc[m][n], 0, 0, 0);
                    acc[m][n] = __builtin_amdgcn_mfma_f32_16x16x32_bf16(
                        wl[n], ah[m], acc[m][n], 0, 0, 0);
                }
        }

        // lane holds chans wc*32+n*16+fq*4..+3 for edge wr*64+m*16+fr
#pragma unroll
        for (int m = 0; m < 4; ++m) {
            const long e = e0 + wr * 64 + m * 16 + fr;
            if (e < N_EDGES) {
#pragma unroll
                for (int n = 0; n < 2; ++n) {
                    ushort4 u;
                    u.x = f2bf(acc[m][n][0]);
                    u.y = f2bf(acc[m][n][1]);
                    u.z = f2bf(acc[m][n][2]);
                    u.w = f2bf(acc[m][n][3]);
                    *(ushort4*)&Ee[e * 128 + wc * 32 + n * 16 + fq * 4] = u;
                }
            }
        }
    }
}

// ---------------------------------------------------------------------------
// CSR scan: single block, 1024 threads.
// ---------------------------------------------------------------------------
__global__ __launch_bounds__(1024) void csr_scan_kernel(
    int* __restrict__ cursor, int* __restrict__ csr_off)
{
    __shared__ int wsum[16];
    const int t = threadIdx.x;
    const int lane = t & 63;
    const int wid = t >> 6;
    const int n0 = t * 100;
    const bool active = (t < 1000);

    int tsum = 0;
    if (active) {
        for (int q = 0; q < 25; ++q) {
            const int4 d = *(const int4*)&cursor[n0 + q * 4];
            tsum += d.x + d.y + d.z + d.w;
        }
    }
    int inc = tsum;
#pragma unroll
    for (int o = 1; o < 64; o <<= 1) {
        const int v = __shfl_up(inc, o, 64);
        if (lane >= o) inc += v;
    }
    if (lane == 63) wsum[wid] = inc;
    __syncthreads();
    if (t == 0) {
        int run = 0;
#pragma unroll
        for (int w = 0; w < 16; ++w) { const int v = wsum[w]; wsum[w] = run; run += v; }
        csr_off[N_NODES] = run;
    }
    __syncthreads();
    if (active) {
        int run = wsum[wid] + inc - tsum;
        for (int q = 0; q < 25; ++q) {
            const int n = n0 + q * 4;
            const int4 d = *(const int4*)&cursor[n];
            int4 offv;
            offv.x = run; run += d.x;
            offv.y = run; run += d.y;
            offv.z = run; run += d.z;
            offv.w = run; run += d.w;
            *(int4*)&csr_off[n] = offv;
            *(int4*)&cursor[n]  = offv;
        }
    }
}

// ---------------------------------------------------------------------------
// CSR fill: one packed int2 {eid, src} store per edge (half the scattered
// cache-line touches of the previous two-array version).
// ---------------------------------------------------------------------------
__global__ __launch_bounds__(256) void csr_fill_kernel(
    const int* __restrict__ ei, int* __restrict__ cursor,
    int2* __restrict__ csr_es)
{
    const int e = blockIdx.x * 256 + threadIdx.x;
    if (e >= N_EDGES) return;
    const int dst = ei[N_EDGES + e];
    const int pos = atomicAdd(&cursor[dst], 1);
    csr_es[pos] = make_int2(e, ei[e]);
}

// ---------------------------------------------------------------------------
// Fused attention, single pass, 8 edges in flight per wave.
// 8-lane group g owns one edge and all 128 ch: lane il holds float4 per head
// at ch = h*32 + il*4. In-group dot reduce: shfl_xor o=1,2,4. Cross-group
// reduce once per node; group 0 writes.
// ---------------------------------------------------------------------------
__global__ __launch_bounds__(256) void fused_attn_kernel(
    const int* __restrict__ csr_off, const int2* __restrict__ csr_es,
    const unsigned short* __restrict__ Ee,
    const float* __restrict__ Qn, const float* __restrict__ Kn,
    const float* __restrict__ Vn, float* __restrict__ out)
{
    const int lane = threadIdx.x & 63;
    const int g = lane >> 3;          // group 0..7 (one edge each)
    const int il = lane & 7;          // lane in group
    const int c4 = il * 4;            // ch offset within head
    const long n = (long)blockIdx.x * 4 + (threadIdx.x >> 6);

    const int off0 = csr_off[n];
    const int off1 = csr_off[n + 1];

    float4 q[4];
#pragma unroll
    for (int h = 0; h < 4; ++h)
        q[h] = *(const float4*)&Qn[n * 128 + h * 32 + c4];

    float dsum[4] = {0.f, 0.f, 0.f, 0.f};
    float4 acc[4];
#pragma unroll
    for (int h = 0; h < 4; ++h) acc[h] = make_float4(0.f, 0.f, 0.f, 0.f);

    for (int base = off0; base < off1; base += 64) {
        const int cnt = min(64, off1 - base);
        int2 es = make_int2(0, 0);
        if (base + lane < off1) es = csr_es[base + lane];

        for (int c0 = 0; c0 < cnt; c0 += 8) {
            const int j = c0 + g;
            const bool valid = (j < cnt);
            const long e = __shfl(es.x, j, 64);
            const long s = __shfl(es.y, j, 64);

            float ph[4];
            float4 ev[4], vv[4];
            if (valid) {
#pragma unroll
                for (int h = 0; h < 4; ++h) {
                    const int ch = h * 32 + c4;
                    const ushort4 u = *(const ushort4*)&Ee[e * 128 + ch];
                    ev[h] = make_float4(bf2f(u.x), bf2f(u.y), bf2f(u.z), bf2f(u.w));
                    const float4 k = *(const float4*)&Kn[s * 128 + ch];
                    vv[h] = *(const float4*)&Vn[s * 128 + ch];
                    ph[h] = q[h].x * (k.x + ev[h].x) + q[h].y * (k.y + ev[h].y) +
                            q[h].z * (k.z + ev[h].z) + q[h].w * (k.w + ev[h].w);
                }
            } else {
#pragma unroll
                for (int h = 0; h < 4; ++h) ph[h] = 0.f;
            }
#pragma unroll
            for (int h = 0; h < 4; ++h) {
#pragma unroll
                for (int o = 1; o < 8; o <<= 1)
                    ph[h] += __shfl_xor(ph[h], o, 64);
            }
            if (valid) {
#pragma unroll
                for (int h = 0; h < 4; ++h) {
                    const float an = __expf(ph[h] * INV_SQRT32 - M0);
                    dsum[h] += an;
                    acc[h].x = fmaf(vv[h].x + ev[h].x, an, acc[h].x);
                    acc[h].y = fmaf(vv[h].y + ev[h].y, an, acc[h].y);
                    acc[h].z = fmaf(vv[h].z + ev[h].z, an, acc[h].z);
                    acc[h].w = fmaf(vv[h].w + ev[h].w, an, acc[h].w);
                }
            }
        }
    }

    // cross-group reduction (lanes il, il+8, ..., il+56 hold same channels)
#pragma unroll
    for (int h = 0; h < 4; ++h) {
#pragma unroll
        for (int o = 8; o < 64; o <<= 1) {
            dsum[h] += __shfl_xor(dsum[h], o, 64);
            acc[h].x += __shfl_xor(acc[h].x, o, 64);
            acc[h].y += __shfl_xor(acc[h].y, o, 64);
            acc[h].z += __shfl_xor(acc[h].z, o, 64);
            acc[h].w += __shfl_xor(acc[h].w, o, 64);
        }
    }

    if (g == 0) {
#pragma unroll
        for (int h = 0; h < 4; ++h) {
            const float rd = 1.f / (dsum[h] + 1e-16f);
            float4 o4 = *(const float4*)&out[n * 128 + h * 32 + c4];
            o4.x = fmaf(acc[h].x, rd, o4.x);
            o4.y = fmaf(acc[h].y, rd, o4.y);
            o4.z = fmaf(acc[h].z, rd, o4.z);
            o4.w = fmaf(acc[h].w, rd, o4.w);
            *(float4*)&out[n * 128 + h * 32 + c4] = o4;
        }
    }
}

// ---------------------------------------------------------------------------
// Workspace layout (float offsets unless noted):
//   Qn      [N,128]   @ 0
//   Kn      [N,128]   @ 12,800,000
//   Vn      [N,128]   @ 25,600,000
//   csr_off [N+1]     @ 38,400,000  (int)
//   cursor  [N]       @ 38,500,004  (int)
//   csr_es  [E] int2  @ 38,600,004  (byte 154,400,016, 8B-aligned)
//   WBh     [65536]us @ 40,000,000
//   WBl     [65536]us @ 40,050,000
//   WEh     [8192]us  @ 40,100,000
//   WEl     [8192]us  @ 40,110,000
//   Ee bf16 [E,128]   @ byte 163,200,032
// ---------------------------------------------------------------------------
extern "C" void kernel_launch(void* const* d_in, const int* in_sizes, int n_in,
                              void* d_out, int out_size, void* d_ws, size_t ws_size,
                              hipStream_t stream)
{
    const float* x  = (const float*)d_in[0];
    const int*   ei = (const int*)d_in[1];
    const float* ea = (const float*)d_in[2];
    const float* Wq = (const float*)d_in[3];
    const float* bq = (const float*)d_in[4];
    const float* Wk = (const float*)d_in[5];
    const float* bk = (const float*)d_in[6];
    const float* Wv = (const float*)d_in[7];
    const float* bv = (const float*)d_in[8];
    const float* We = (const float*)d_in[9];
    const float* Ws = (const float*)d_in[10];
    const float* bs = (const float*)d_in[11];
    float* out = (float*)d_out;

    float* ws = (float*)d_ws;
    float* Qn = ws;
    float* Kn = ws + 12800000;
    float* Vn = ws + 25600000;
    int* csr_off = (int*)(ws + 38400000);
    int* cursor  = (int*)(ws + 38500004);
    int2* csr_es = (int2*)(ws + 38600004);
    unsigned short* WBh = (unsigned short*)(ws + 40000000);
    unsigned short* WBl = (unsigned short*)(ws + 40050000);
    unsigned short* WEh = (unsigned short*)(ws + 40100000);
    unsigned short* WEl = (unsigned short*)(ws + 40110000);
    unsigned short* Ee = (unsigned short*)((char*)d_ws + 163200032);

    prep_kernel<<<391, 256, 0, stream>>>(Wq, Wk, Wv, Ws, We,
                                         WBh, WBl, WEh, WEl, cursor);

    mega_kernel<<<GRID_MEGA, 512, 0, stream>>>(x, ei, ea,
                                               WBh, WBl, WEh, WEl,
                                               bq, bk, bv, bs,
                                               Qn, Kn, Vn, out, Ee, cursor);

    csr_scan_kernel<<<1, 1024, 0, stream>>>(cursor, csr_off);

    csr_fill_kernel<<<(N_EDGES + 255) / 256, 256, 0, stream>>>(ei, cursor, csr_es);

    fused_attn_kernel<<<25000, 256, 0, stream>>>(csr_off, csr_es, Ee,
                                                 Qn, Kn, Vn, out);
}

// Round 7
// 551.432 us; speedup vs baseline: 1.3031x; 1.0901x over previous
//
#include <hip/hip_runtime.h>
#include <hip/hip_bf16.h>
#include <math.h>

#define N_NODES 100000
#define N_EDGES 500000
#define M0 8.0f
#define INV_SQRT32 0.17677669529663687f

#define NB_PROJ 1563   // ceil(100000/64)
#define NB_EE   3907   // ceil(500000/128)  (each ee block also hists its 128 edges)
#define GRID_MEGA (NB_PROJ + NB_EE)

typedef __attribute__((ext_vector_type(8))) short bf16x8;
typedef __attribute__((ext_vector_type(4))) float f32x4;
typedef __attribute__((ext_vector_type(8))) unsigned short us8;

static __device__ __forceinline__ unsigned short f2bf(float f) {
    __hip_bfloat16 h = __float2bfloat16(f);
    return *(unsigned short*)&h;
}

static __device__ __forceinline__ void split4(float4 v, ushort4& hv, ushort4& lv) {
    const unsigned short h0 = f2bf(v.x), h1 = f2bf(v.y),
                         h2 = f2bf(v.z), h3 = f2bf(v.w);
    hv.x = h0; hv.y = h1; hv.z = h2; hv.w = h3;
    lv.x = f2bf(v.x - __uint_as_float((unsigned)h0 << 16));
    lv.y = f2bf(v.y - __uint_as_float((unsigned)h1 << 16));
    lv.z = f2bf(v.z - __uint_as_float((unsigned)h2 << 16));
    lv.w = f2bf(v.w - __uint_as_float((unsigned)h3 << 16));
}

// direct global->LDS DMA, 16 B per lane
static __device__ __forceinline__ void gl_lds16(
    const unsigned short* __restrict__ g, unsigned short* l)
{
    __builtin_amdgcn_global_load_lds(
        (const __attribute__((address_space(1))) unsigned int*)g,
        (__attribute__((address_space(3))) unsigned int*)l, 16, 0, 0);
}

// ---------------------------------------------------------------------------
// prep: split weights into bf16 hi/lo (Markidis) AND zero the cursor array.
// ---------------------------------------------------------------------------
__global__ __launch_bounds__(256) void prep_kernel(
    const float* __restrict__ Wq, const float* __restrict__ Wk,
    const float* __restrict__ Wv, const float* __restrict__ Ws,
    const float* __restrict__ We,
    unsigned short* __restrict__ WBh, unsigned short* __restrict__ WBl,
    unsigned short* __restrict__ WEh, unsigned short* __restrict__ WEl,
    int* __restrict__ cursor)
{
    const int i = blockIdx.x * 256 + threadIdx.x;
    if (i < N_NODES) cursor[i] = 0;
    if (i < 65536) {
        const int p = i >> 14;
        const float* W = (p == 0) ? Wq : (p == 1) ? Wk : (p == 2) ? Wv : Ws;
        const float v = W[i & 16383];
        const unsigned short h = f2bf(v);
        WBh[i] = h;
        WBl[i] = f2bf(v - __uint_as_float((unsigned)h << 16));
    } else if (i < 73728) {
        const int idx = i - 65536;
        const float v = We[idx];
        const unsigned short h = f2bf(v);
        WEh[idx] = h;
        WEl[idx] = f2bf(v - __uint_as_float((unsigned)h << 16));
    }
}

// ---------------------------------------------------------------------------
// mega: node-proj MFMA + edge-embed MFMA (each ee block also histograms its
// own 128 edges). R3-verified structure; W staging now via global_load_lds
// width=16 with PRE-SWIZZLED SOURCE + linear LDS dest: dest slot d of row r
// receives source slot d^(r&7)  (content identical to the old reg-staged
// swizzled write; MFMA read indices unchanged).
// ---------------------------------------------------------------------------
__global__ __launch_bounds__(512, 4) void mega_kernel(
    const float* __restrict__ x, const int* __restrict__ ei,
    const float* __restrict__ ea,
    const unsigned short* __restrict__ WBh, const unsigned short* __restrict__ WBl,
    const unsigned short* __restrict__ WEh, const unsigned short* __restrict__ WEl,
    const float* __restrict__ bq, const float* __restrict__ bk,
    const float* __restrict__ bv, const float* __restrict__ bs,
    float* __restrict__ Qn, float* __restrict__ Kn, float* __restrict__ Vn,
    float* __restrict__ out, unsigned short* __restrict__ Ee,
    int* __restrict__ cursor)
{
    __shared__ __align__(16) unsigned short sAh[8192];
    __shared__ __align__(16) unsigned short sAl[8192];
    __shared__ __align__(16) unsigned short sWh[8192];
    __shared__ __align__(16) unsigned short sWl[8192];

    const int t = threadIdx.x;
    const int bid = blockIdx.x;

    const int lane = t & 63;
    const int wid = t >> 6;          // 0..7
    const int fr = lane & 15;
    const int fq = lane >> 4;

    if (bid < NB_PROJ) {
        // ---- node projection: 64 rows x (Q,K,V,S); wave owns 16 ch ----
        const long r0 = (long)bid * 64;

        for (int i = t; i < 2048; i += 512) {
            const int r = i >> 5;
            const int k4 = (i & 31) * 4;
            const long row = r0 + r;
            float4 v = (row < N_NODES) ? *(const float4*)&x[row * 128 + k4]
                                       : make_float4(0.f, 0.f, 0.f, 0.f);
            ushort4 hv, lv; split4(v, hv, lv);
            const int di = r * 128 + (k4 ^ ((r & 7) << 3));
            *(ushort4*)&sAh[di] = hv;
            *(ushort4*)&sAl[di] = lv;
        }

        for (int p = 0; p < 4; ++p) {
            const float* bias = (p == 0) ? bq : (p == 1) ? bk : (p == 2) ? bv : bs;
            float* dst        = (p == 0) ? Qn : (p == 1) ? Kn : (p == 2) ? Vn : out;

            f32x4 acc[4];
#pragma unroll
            for (int m = 0; m < 4; ++m) acc[m] = (f32x4){0.f, 0.f, 0.f, 0.f};

            for (int kc = 0; kc < 2; ++kc) {
                __syncthreads();   // prev phase's LDS reads done
                // W chunk [128 ch][64 k] hi/lo via LDS-DMA, pre-swz source
#pragma unroll
                for (int c = 0; c < 2; ++c) {
                    const int i = c * 512 + t;
                    const int r = i >> 3;
                    const int d = i & 7;
                    const int gi = p * 16384 + r * 128 + kc * 64 + ((d ^ (r & 7)) * 8);
                    gl_lds16(&WBh[gi], &sWh[i * 8]);
                    gl_lds16(&WBl[gi], &sWl[i * 8]);
                }
                __syncthreads();   // drains vmcnt -> LDS contents valid

#pragma unroll
                for (int ks = 0; ks < 2; ++ks) {
                    const int kx = kc * 64 + ks * 32 + fq * 8;
                    const int kw = ks * 32 + fq * 8;
                    bf16x8 ah[4], al[4], wh, wl;
#pragma unroll
                    for (int m = 0; m < 4; ++m) {
                        const int r = m * 16 + fr;
                        const int di = r * 128 + (kx ^ ((r & 7) << 3));
                        ah[m] = *(const bf16x8*)&sAh[di];
                        al[m] = *(const bf16x8*)&sAl[di];
                    }
                    {
                        const int r = wid * 16 + fr;
                        const int di = r * 64 + (kw ^ ((r & 7) << 3));
                        wh = *(const bf16x8*)&sWh[di];
                        wl = *(const bf16x8*)&sWl[di];
                    }
#pragma unroll
                    for (int m = 0; m < 4; ++m) {
                        acc[m] = __builtin_amdgcn_mfma_f32_16x16x32_bf16(
                            ah[m], wh, acc[m], 0, 0, 0);
                        acc[m] = __builtin_amdgcn_mfma_f32_16x16x32_bf16(
                            ah[m], wl, acc[m], 0, 0, 0);
                        acc[m] = __builtin_amdgcn_mfma_f32_16x16x32_bf16(
                            al[m], wh, acc[m], 0, 0, 0);
                    }
                }
            }

            const float bb = bias[wid * 16 + fr];
#pragma unroll
            for (int m = 0; m < 4; ++m) {
                const long rowb = r0 + m * 16 + fq * 4;
#pragma unroll
                for (int j = 0; j < 4; ++j) {
                    if (rowb + j < N_NODES)
                        dst[(rowb + j) * 128 + wid * 16 + fr] = acc[m][j] + bb;
                }
            }
        }
    } else {
        // ---- edge embedding GEMM (+ own-tile histogram) ----
        const long e0 = (long)(bid - NB_PROJ) * 128;
        const int wr = wid >> 2;     // 0..1: edge rows wr*64
        const int wc = wid & 3;      // 0..3: ch cols wc*32

        // histogram for this block's 128 edges (independent of GEMM)
        if (t < 128) {
            const long e = e0 + t;
            if (e < N_EDGES) atomicAdd(&cursor[ei[N_EDGES + e]], 1);
        }

        // We [128 ch][64 k] hi/lo via LDS-DMA, pre-swz source
#pragma unroll
        for (int c = 0; c < 2; ++c) {
            const int i = c * 512 + t;
            const int r = i >> 3;
            const int d = i & 7;
            const int gi = r * 64 + ((d ^ (r & 7)) * 8);
            gl_lds16(&WEh[gi], &sWh[i * 8]);
            gl_lds16(&WEl[gi], &sWl[i * 8]);
        }
        // ea tile [128][64] -> hi/lo (VALU split; can't DMA)
        for (int i = t; i < 2048; i += 512) {
            const int r = i >> 4;
            const int k4 = (i & 15) * 4;
            const long e = e0 + r;
            float4 v = (e < N_EDGES) ? *(const float4*)&ea[e * 64 + k4]
                                     : make_float4(0.f, 0.f, 0.f, 0.f);
            ushort4 hv, lv; split4(v, hv, lv);
            const int di = r * 64 + (k4 ^ ((r & 7) << 3));
            *(ushort4*)&sAh[di] = hv;
            *(ushort4*)&sAl[di] = lv;
        }
        __syncthreads();

        f32x4 acc[4][2];
#pragma unroll
        for (int m = 0; m < 4; ++m)
#pragma unroll
            for (int n = 0; n < 2; ++n) acc[m][n] = (f32x4){0.f, 0.f, 0.f, 0.f};

#pragma unroll
        for (int ks = 0; ks < 2; ++ks) {
            const int kk = ks * 32 + fq * 8;
            bf16x8 ah[4], al[4], wh[2], wl[2];
#pragma unroll
            for (int m = 0; m < 4; ++m) {
                const int r = wr * 64 + m * 16 + fr;
                const int di = r * 64 + (kk ^ ((r & 7) << 3));
                ah[m] = *(const bf16x8*)&sAh[di];
                al[m] = *(const bf16x8*)&sAl[di];
            }
#pragma unroll
            for (int n = 0; n < 2; ++n) {
                const int r = wc * 32 + n * 16 + fr;
                const int di = r * 64 + (kk ^ ((r & 7) << 3));
                wh[n] = *(const bf16x8*)&sWh[di];
                wl[n] = *(const bf16x8*)&sWl[di];
            }
#pragma unroll
            for (int m = 0; m < 4; ++m)
#pragma unroll
                for (int n = 0; n < 2; ++n) {
                    acc[m][n] = __builtin_amdgcn_mfma_f32_16x16x32_bf16(
                        ah[m], wh[n], acc[m][n], 0, 0, 0);
                    acc[m][n] = __builtin_amdgcn_mfma_f32_16x16x32_bf16(
                        ah[m], wl[n], acc[m][n], 0, 0, 0);
                    acc[m][n] = __builtin_amdgcn_mfma_f32_16x16x32_bf16(
                        al[m], wh[n], acc[m][n], 0, 0, 0);
                }
        }

#pragma unroll
        for (int m = 0; m < 4; ++m) {
            const long e = e0 + wr * 64 + m * 16 + fq * 4;
#pragma unroll
            for (int j = 0; j < 4; ++j) {
                if (e + j < N_EDGES) {
#pragma unroll
                    for (int n = 0; n < 2; ++n)
                        Ee[(e + j) * 128 + wc * 32 + n * 16 + fr] =
                            f2bf(acc[m][n][j]);
                }
            }
        }
    }
}

// ---------------------------------------------------------------------------
// CSR scan: single block, 1024 threads.
// ---------------------------------------------------------------------------
__global__ __launch_bounds__(1024) void csr_scan_kernel(
    int* __restrict__ cursor, int* __restrict__ csr_off)
{
    __shared__ int wsum[16];
    const int t = threadIdx.x;
    const int lane = t & 63;
    const int wid = t >> 6;
    const int n0 = t * 100;
    const bool active = (t < 1000);

    int tsum = 0;
    if (active) {
        for (int q = 0; q < 25; ++q) {
            const int4 d = *(const int4*)&cursor[n0 + q * 4];
            tsum += d.x + d.y + d.z + d.w;
        }
    }
    int inc = tsum;
#pragma unroll
    for (int o = 1; o < 64; o <<= 1) {
        const int v = __shfl_up(inc, o, 64);
        if (lane >= o) inc += v;
    }
    if (lane == 63) wsum[wid] = inc;
    __syncthreads();
    if (t == 0) {
        int run = 0;
#pragma unroll
        for (int w = 0; w < 16; ++w) { const int v = wsum[w]; wsum[w] = run; run += v; }
        csr_off[N_NODES] = run;
    }
    __syncthreads();
    if (active) {
        int run = wsum[wid] + inc - tsum;
        for (int q = 0; q < 25; ++q) {
            const int n = n0 + q * 4;
            const int4 d = *(const int4*)&cursor[n];
            int4 offv;
            offv.x = run; run += d.x;
            offv.y = run; run += d.y;
            offv.z = run; run += d.z;
            offv.w = run; run += d.w;
            *(int4*)&csr_off[n] = offv;
            *(int4*)&cursor[n]  = offv;
        }
    }
}

// ---------------------------------------------------------------------------
// CSR fill: one packed int2 {eid, src} store per edge.
// ---------------------------------------------------------------------------
__global__ __launch_bounds__(256) void csr_fill_kernel(
    const int* __restrict__ ei, int* __restrict__ cursor,
    int2* __restrict__ csr_es)
{
    const int e = blockIdx.x * 256 + threadIdx.x;
    if (e >= N_EDGES) return;
    const int dst = ei[N_EDGES + e];
    const int pos = atomicAdd(&cursor[dst], 1);
    csr_es[pos] = make_int2(e, ei[e]);
}

// ---------------------------------------------------------------------------
// Fused attention: single pass, serial edge broadcast (R2 form — empirical
// best: all 64 lanes read ONE K/V/Ee row -> fully coalesced 512-B fetches).
// Lane owns channels {2l, 2l+1}; head h = lane>>4; 4-level shfl_xor reduce.
// ---------------------------------------------------------------------------
__global__ __launch_bounds__(256) void fused_attn_kernel(
    const int* __restrict__ csr_off, const int2* __restrict__ csr_es,
    const unsigned short* __restrict__ Ee,
    const float* __restrict__ Qn, const float* __restrict__ Kn,
    const float* __restrict__ Vn, float* __restrict__ out)
{
    const int lane = threadIdx.x & 63;
    const int l2 = lane * 2;
    const long n = (long)blockIdx.x * 4 + (threadIdx.x >> 6);

    const int off0 = csr_off[n];
    const int off1 = csr_off[n + 1];
    const float2 q = *(const float2*)&Qn[n * 128 + l2];

    float dsum = 0.f;
    float2 acc = make_float2(0.f, 0.f);
    for (int base = off0; base < off1; base += 64) {
        const int cnt = min(64, off1 - base);
        int2 es = make_int2(0, 0);
        if (base + lane < off1) es = csr_es[base + lane];
        for (int j = 0; j < cnt; ++j) {
            const long e = __shfl(es.x, j, 64);
            const long s = __shfl(es.y, j, 64);
            const unsigned u = *(const unsigned*)&Ee[e * 128 + l2];
            const float2 k = *(const float2*)&Kn[s * 128 + l2];
            const float ea0 = __uint_as_float(u << 16);
            const float ea1 = __uint_as_float(u & 0xffff0000u);
            float p = q.x * (k.x + ea0) + q.y * (k.y + ea1);
#pragma unroll
            for (int o = 1; o < 16; o <<= 1) p += __shfl_xor(p, o, 64);
            const float an = __expf(p * INV_SQRT32 - M0);
            dsum += an;
            const float2 v = *(const float2*)&Vn[s * 128 + l2];
            acc.x = fmaf(v.x + ea0, an, acc.x);
            acc.y = fmaf(v.y + ea1, an, acc.y);
        }
    }
    const float rd = 1.f / (dsum + 1e-16f);
    float2 o = *(const float2*)&out[n * 128 + l2];
    o.x = fmaf(acc.x, rd, o.x);
    o.y = fmaf(acc.y, rd, o.y);
    *(float2*)&out[n * 128 + l2] = o;
}

// ---------------------------------------------------------------------------
// Workspace layout (float offsets unless noted):
//   Qn      [N,128]   @ 0
//   Kn      [N,128]   @ 12,800,000
//   Vn      [N,128]   @ 25,600,000
//   csr_off [N+1]     @ 38,400,000  (int)
//   cursor  [N]       @ 38,500,004  (int)
//   csr_es  [E] int2  @ 38,600,004  (byte 154,400,016, 8B-aligned)
//   WBh     [65536]us @ 40,000,000
//   WBl     [65536]us @ 40,050,000
//   WEh     [8192]us  @ 40,100,000
//   WEl     [8192]us  @ 40,110,000
//   Ee bf16 [E,128]   @ byte 163,200,032
// ---------------------------------------------------------------------------
extern "C" void kernel_launch(void* const* d_in, const int* in_sizes, int n_in,
                              void* d_out, int out_size, void* d_ws, size_t ws_size,
                              hipStream_t stream)
{
    const float* x  = (const float*)d_in[0];
    const int*   ei = (const int*)d_in[1];
    const float* ea = (const float*)d_in[2];
    const float* Wq = (const float*)d_in[3];
    const float* bq = (const float*)d_in[4];
    const float* Wk = (const float*)d_in[5];
    const float* bk = (const float*)d_in[6];
    const float* Wv = (const float*)d_in[7];
    const float* bv = (const float*)d_in[8];
    const float* We = (const float*)d_in[9];
    const float* Ws = (const float*)d_in[10];
    const float* bs = (const float*)d_in[11];
    float* out = (float*)d_out;

    float* ws = (float*)d_ws;
    float* Qn = ws;
    float* Kn = ws + 12800000;
    float* Vn = ws + 25600000;
    int* csr_off = (int*)(ws + 38400000);
    int* cursor  = (int*)(ws + 38500004);
    int2* csr_es = (int2*)(ws + 38600004);
    unsigned short* WBh = (unsigned short*)(ws + 40000000);
    unsigned short* WBl = (unsigned short*)(ws + 40050000);
    unsigned short* WEh = (unsigned short*)(ws + 40100000);
    unsigned short* WEl = (unsigned short*)(ws + 40110000);
    unsigned short* Ee = (unsigned short*)((char*)d_ws + 163200032);

    prep_kernel<<<391, 256, 0, stream>>>(Wq, Wk, Wv, Ws, We,
                                         WBh, WBl, WEh, WEl, cursor);

    mega_kernel<<<GRID_MEGA, 512, 0, stream>>>(x, ei, ea,
                                               WBh, WBl, WEh, WEl,
                                               bq, bk, bv, bs,
                                               Qn, Kn, Vn, out, Ee, cursor);

    csr_scan_kernel<<<1, 1024, 0, stream>>>(cursor, csr_off);

    csr_fill_kernel<<<(N_EDGES + 255) / 256, 256, 0, stream>>>(ei, cursor, csr_es);

    fused_attn_kernel<<<25000, 256, 0, stream>>>(csr_off, csr_es, Ee,
                                                 Qn, Kn, Vn, out);
}